// Round 16
// baseline (66.182 us; speedup 1.0000x reference)
//
#include <hip/hip_runtime.h>
#include <hip/hip_bf16.h>

#define B_ 2
#define T_ 4096
#define D_ 2048
#define H_ 4
#define NC 176            // combined proj cols: 128 q | 32 k | 4 w | 12 pad
#define ROWS (B_ * T_)    // 8192
#define TILE_E (16 * NC)  // 2816 elems per 16-row tile of Cb2
#define WTILE_E (16 * D_) // 32768 elems per 16-row n-tile of Wcb2

typedef __attribute__((ext_vector_type(8))) short short8;   // 8 x bf16
typedef __attribute__((ext_vector_type(4))) short short4v;  // 4 x bf16
typedef __attribute__((ext_vector_type(4))) float f32x4;
typedef __attribute__((ext_vector_type(4))) float float4v;

__device__ inline unsigned short f2bf(float f) {
  unsigned u = __float_as_uint(f);
  u += 0x7fffu + ((u >> 16) & 1u);   // RNE
  return (unsigned short)(u >> 16);
}
__device__ inline float bf2f(unsigned short s) {
  return __uint_as_float(((unsigned)s) << 16);
}

// ---------------- Kernel 1: pack weights into octet-tiled bf16 (vectorized) -
// Wcb2 layout: E(n, r, k) = n*32768 + (k>>3)*128 + r*8 + (k&7)
__global__ __launch_bounds__(256) void pack_weights(const float* __restrict__ Wq,
                                                    const float* __restrict__ Ww,
                                                    const float* __restrict__ Wk,
                                                    unsigned short* __restrict__ Wcb) {
  int row = blockIdx.x;          // 0..175
  int cg  = threadIdx.x;         // 0..255 (D_/8 octets)
  int col = cg * 8;

  const float* src = nullptr;
  if (row < 128)       src = Wq + (size_t)row * D_;
  else if (row < 160)  src = Wk + (size_t)(row - 128) * D_;
  else if (row < 164)  src = Ww + (size_t)(row - 160) * D_;

  short8 v;
  if (src) {
    float4v f0 = *(const float4v*)(src + col);
    float4v f1 = *(const float4v*)(src + col + 4);
#pragma unroll
    for (int i = 0; i < 4; ++i) {
      v[i]     = (short)f2bf(f0[i]);
      v[i + 4] = (short)f2bf(f1[i]);
    }
  } else {
#pragma unroll
    for (int i = 0; i < 8; ++i) v[i] = 0;
  }
  int n = row >> 4, r = row & 15;
  *(short8*)&Wcb[(size_t)n * WTILE_E + (size_t)cg * 128 + r * 8] = v;
}

// ---------------- Kernel 2: proj v12 = v8 compute + 49KB 4-phase reduce -----
// M_rep=2 x split-K=8. 256 blocks x 8 waves (512 thr). Block = 32 rows;
// wave w owns K-chunk [w*256,(w+1)*256) for BOTH m-tiles (B reuse x2).
// Reduce in 4 phases (2 m x 2 n-groups) through red[8][6][64] = 49 KB.
// launch_bounds (512,2): compiler lands ~116 VGPR (R9-measured) <= 128 ->
// 2 blocks/CU = 16 waves/CU. R13's regression was the (512,4) VGPR cap, not
// the 4-phase reduce. If VGPR > 128 we fall back to 1 block/CU = v8 perf.
__global__ __launch_bounds__(512, 2) void proj_kernel(const float* __restrict__ hs,
                                                      const unsigned short* __restrict__ Wcb,
                                                      unsigned short* __restrict__ Cb) {
  __shared__ f32x4 red[8][6][64];   // 49,152 B

  int wid  = threadIdx.x >> 6;
  int lane = threadIdx.x & 63;
  int lr = lane & 15, lo = lane >> 4;
  int row0 = blockIdx.x * 32;
  int k0   = wid * 256;

  const float* ap0 = hs + (size_t)(row0 + lr) * D_ + k0 + lo * 8;
  const float* ap1 = ap0 + (size_t)16 * D_;
  const unsigned short* bbase = Wcb + (size_t)k0 * 16 + lo * 128 + lr * 8;

  f32x4 acc0[11], acc1[11];
#pragma unroll
  for (int n = 0; n < 11; ++n) {
    acc0[n] = (f32x4){0.f, 0.f, 0.f, 0.f};
    acc1[n] = (f32x4){0.f, 0.f, 0.f, 0.f};
  }

  float4v Am0[2][2], Am1[2][2];   // [buf][half]
  short8  Bv[2][11];

  Am0[0][0] = *(const float4v*)(ap0);
  Am0[0][1] = *(const float4v*)(ap0 + 4);
  Am1[0][0] = *(const float4v*)(ap1);
  Am1[0][1] = *(const float4v*)(ap1 + 4);
#pragma unroll
  for (int n = 0; n < 11; ++n)
    Bv[0][n] = *(const short8*)(bbase + (size_t)n * WTILE_E);

#pragma unroll
  for (int s = 0; s < 8; ++s) {
    const int cur = s & 1, nxt = cur ^ 1;
    if (s < 7) {   // issue next-step loads BEFORE this step's MFMAs
      Am0[nxt][0] = *(const float4v*)(ap0 + (s + 1) * 32);
      Am0[nxt][1] = *(const float4v*)(ap0 + (s + 1) * 32 + 4);
      Am1[nxt][0] = *(const float4v*)(ap1 + (s + 1) * 32);
      Am1[nxt][1] = *(const float4v*)(ap1 + (s + 1) * 32 + 4);
#pragma unroll
      for (int n = 0; n < 11; ++n)
        Bv[nxt][n] = *(const short8*)(bbase + (size_t)n * WTILE_E + (s + 1) * 512);
    }
    short8 a0, a1;
#pragma unroll
    for (int i = 0; i < 4; ++i) {
      a0[i]     = (short)f2bf(Am0[cur][0][i]);
      a0[i + 4] = (short)f2bf(Am0[cur][1][i]);
      a1[i]     = (short)f2bf(Am1[cur][0][i]);
      a1[i + 4] = (short)f2bf(Am1[cur][1][i]);
    }
#pragma unroll
    for (int n = 0; n < 11; ++n) {
      acc0[n] = __builtin_amdgcn_mfma_f32_16x16x32_bf16(a0, Bv[cur][n], acc0[n], 0, 0, 0);
      acc1[n] = __builtin_amdgcn_mfma_f32_16x16x32_bf16(a1, Bv[cur][n], acc1[n], 0, 0, 0);
    }
  }

  // 4-phase 8-way reduce (m-tile ph x n-group g); wave w finalizes n = ns+w.
#pragma unroll
  for (int ph = 0; ph < 2; ++ph) {
    unsigned short* cb = Cb + (size_t)((row0 >> 4) + ph) * TILE_E + (lr & 7);
#pragma unroll
    for (int g = 0; g < 2; ++g) {
      const int ns = g * 6;
      const int cnt = (g == 0) ? 6 : 5;
#pragma unroll
      for (int j = 0; j < 6; ++j)
        if (j < cnt) red[wid][j][lane] = ph == 0 ? acc0[ns + j] : acc1[ns + j];
      __syncthreads();
      if (wid < cnt) {
        int n = ns + wid;
        f32x4 t = red[0][wid][lane];
#pragma unroll
        for (int w = 1; w < 8; ++w) {
          f32x4 p = red[w][wid][lane];
#pragma unroll
          for (int r = 0; r < 4; ++r) t[r] += p[r];
        }
        int oct = n * 2 + (lr >> 3);
#pragma unroll
        for (int r = 0; r < 4; ++r)
          cb[oct * 128 + (lo * 4 + r) * 8] = f2bf(t[r]);
      }
      __syncthreads();
    }
  }
}

// ---------------- Kernel 3: score v7 — 16x512 block tile (R14 best) ---------
__global__ __launch_bounds__(256) void score_kernel(const unsigned short* __restrict__ Cb,
                                                    float* __restrict__ out) {
  int b = blockIdx.z;
  int wid  = threadIdx.x >> 6;
  int lane = threadIdx.x & 63;
  int lr = lane & 15, lo = lane >> 4;
  int t_base = blockIdx.y * 16;
  int s_base = blockIdx.x * 512 + wid * 128;

  const unsigned short* C2 = Cb + (size_t)b * (T_ / 16) * TILE_E;
  float* O = out + (size_t)b * T_ * T_;

  const unsigned short* Ct = C2 + (size_t)(t_base >> 4) * TILE_E;

  // q-fragments + w for this block's single m-tile
  short8 af[H_];
#pragma unroll
  for (int h = 0; h < H_; ++h)
    af[h] = *(const short8*)(Ct + (h * 4 + lo) * 128 + lr * 8);

  float wv[4][H_];
#pragma unroll
  for (int r = 0; r < 4; ++r) {
    short4v wr = *(const short4v*)(Ct + 20 * 128 + lo * 32 + r * 8);
#pragma unroll
    for (int h = 0; h < H_; ++h) wv[r][h] = bf2f((unsigned short)wr[h]);
  }

  // k-fragments for this wave's 8 s-tiles
  short8 bf[8];
#pragma unroll
  for (int n = 0; n < 8; ++n)
    bf[n] = *(const short8*)(C2 + (size_t)((s_base >> 4) + n) * TILE_E +
                             (16 + lo) * 128 + lr * 8);

  const f32x4 zero = (f32x4){0.f, 0.f, 0.f, 0.f};

  int tc = t_base + lo * 4;
  float* rowp[4];
#pragma unroll
  for (int r = 0; r < 4; ++r)
    rowp[r] = O + (size_t)(tc + r) * T_ + s_base + lr;

#pragma unroll
  for (int n = 0; n < 8; ++n) {
    f32x4 o = zero;
#pragma unroll
    for (int h = 0; h < H_; ++h) {
      f32x4 c = __builtin_amdgcn_mfma_f32_16x16x32_bf16(af[h], bf[n], zero, 0, 0, 0);
#pragma unroll
      for (int r = 0; r < 4; ++r) o[r] += wv[r][h] * fmaxf(c[r], 0.f);
    }
#pragma unroll
    for (int r = 0; r < 4; ++r)
      rowp[r][n * 16] = o[r];   // compile-time offset -> store immediate
  }
}

// ---------------------------------------------------------------------------
extern "C" void kernel_launch(void* const* d_in, const int* in_sizes, int n_in,
                              void* d_out, int out_size, void* d_ws, size_t ws_size,
                              hipStream_t stream) {
  const float* hs = (const float*)d_in[0];
  const float* Wq = (const float*)d_in[1];
  const float* Ww = (const float*)d_in[2];
  const float* Wk = (const float*)d_in[3];
  float* out = (float*)d_out;

  unsigned short* Wcb = (unsigned short*)d_ws;                      // 720,896 B
  unsigned short* Cb  = (unsigned short*)((char*)d_ws + (1 << 20)); // 2,883,584 B

  pack_weights<<<NC, 256, 0, stream>>>(Wq, Ww, Wk, Wcb);
  proj_kernel<<<ROWS / 32, 512, 0, stream>>>(hs, Wcb, Cb);
  dim3 g(T_ / 512, T_ / 16, B_);
  score_kernel<<<g, 256, 0, stream>>>(Cb, out);
}

// Round 17
// 58.260 us; speedup vs baseline: 1.1360x; 1.1360x over previous
//
#include <hip/hip_runtime.h>
#include <hip/hip_bf16.h>

#define B_ 2
#define T_ 4096
#define D_ 2048
#define H_ 4
#define NC 176            // combined proj cols: 128 q | 32 k | 4 w | 12 pad
#define ROWS (B_ * T_)    // 8192
#define TILE_E (16 * NC)  // 2816 elems per 16-row tile of Cb2
#define WTILE_E (16 * D_) // 32768 elems per 16-row n-tile of Wcb2

typedef __attribute__((ext_vector_type(8))) short short8;   // 8 x bf16
typedef __attribute__((ext_vector_type(4))) short short4v;  // 4 x bf16
typedef __attribute__((ext_vector_type(4))) float f32x4;
typedef __attribute__((ext_vector_type(4))) float float4v;

__device__ inline unsigned short f2bf(float f) {
  unsigned u = __float_as_uint(f);
  u += 0x7fffu + ((u >> 16) & 1u);   // RNE
  return (unsigned short)(u >> 16);
}
__device__ inline float bf2f(unsigned short s) {
  return __uint_as_float(((unsigned)s) << 16);
}

// ---------------- Kernel 1: pack weights into octet-tiled bf16 (vectorized) -
// Wcb2 layout: E(n, r, k) = n*32768 + (k>>3)*128 + r*8 + (k&7)
__global__ __launch_bounds__(256) void pack_weights(const float* __restrict__ Wq,
                                                    const float* __restrict__ Ww,
                                                    const float* __restrict__ Wk,
                                                    unsigned short* __restrict__ Wcb) {
  int row = blockIdx.x;          // 0..175
  int cg  = threadIdx.x;         // 0..255 (D_/8 octets)
  int col = cg * 8;

  const float* src = nullptr;
  if (row < 128)       src = Wq + (size_t)row * D_;
  else if (row < 160)  src = Wk + (size_t)(row - 128) * D_;
  else if (row < 164)  src = Ww + (size_t)(row - 160) * D_;

  short8 v;
  if (src) {
    float4v f0 = *(const float4v*)(src + col);
    float4v f1 = *(const float4v*)(src + col + 4);
#pragma unroll
    for (int i = 0; i < 4; ++i) {
      v[i]     = (short)f2bf(f0[i]);
      v[i + 4] = (short)f2bf(f1[i]);
    }
  } else {
#pragma unroll
    for (int i = 0; i < 8; ++i) v[i] = 0;
  }
  int n = row >> 4, r = row & 15;
  *(short8*)&Wcb[(size_t)n * WTILE_E + (size_t)cg * 128 + r * 8] = v;
}

// ---------------- Kernel 2: proj v13 = v8 + PINNED prefetch pipeline --------
// M_rep=2 x split-K=8. 256 blocks x 8 waves (512 thr). Block = 32 rows;
// wave w owns K-chunk [w*256,(w+1)*256) for BOTH m-tiles.
// v8's VGPR=116 < declared-buffer count (~190) => compiler was COLLAPSING the
// register double-buffer (prefetch became load-just-before-use). Each step now
// issues all 15 next-step loads, then sched_barrier(0) pins them above the
// MFMAs. Latency-bound loop (~80% idle) => fence-order cost is small.
// NOTE: (512,2) — (512,4) caps VGPR at 128 -> spill (R13). Do not tighten.
__global__ __launch_bounds__(512, 2) void proj_kernel(const float* __restrict__ hs,
                                                      const unsigned short* __restrict__ Wcb,
                                                      unsigned short* __restrict__ Cb) {
  __shared__ f32x4 red[8][11][64];   // 90,112 B -> 1 block/CU (8 waves/CU)

  int wid  = threadIdx.x >> 6;
  int lane = threadIdx.x & 63;
  int lr = lane & 15, lo = lane >> 4;
  int row0 = blockIdx.x * 32;
  int k0   = wid * 256;

  const float* ap0 = hs + (size_t)(row0 + lr) * D_ + k0 + lo * 8;
  const float* ap1 = ap0 + (size_t)16 * D_;
  const unsigned short* bbase = Wcb + (size_t)k0 * 16 + lo * 128 + lr * 8;

  f32x4 acc0[11], acc1[11];
#pragma unroll
  for (int n = 0; n < 11; ++n) {
    acc0[n] = (f32x4){0.f, 0.f, 0.f, 0.f};
    acc1[n] = (f32x4){0.f, 0.f, 0.f, 0.f};
  }

  float4v Am0[2][2], Am1[2][2];   // [buf][half]
  short8  Bv[2][11];

  Am0[0][0] = *(const float4v*)(ap0);
  Am0[0][1] = *(const float4v*)(ap0 + 4);
  Am1[0][0] = *(const float4v*)(ap1);
  Am1[0][1] = *(const float4v*)(ap1 + 4);
#pragma unroll
  for (int n = 0; n < 11; ++n)
    Bv[0][n] = *(const short8*)(bbase + (size_t)n * WTILE_E);

#pragma unroll
  for (int s = 0; s < 8; ++s) {
    const int cur = s & 1, nxt = cur ^ 1;
    if (s < 7) {   // issue ALL next-step loads first...
      Am0[nxt][0] = *(const float4v*)(ap0 + (s + 1) * 32);
      Am0[nxt][1] = *(const float4v*)(ap0 + (s + 1) * 32 + 4);
      Am1[nxt][0] = *(const float4v*)(ap1 + (s + 1) * 32);
      Am1[nxt][1] = *(const float4v*)(ap1 + (s + 1) * 32 + 4);
#pragma unroll
      for (int n = 0; n < 11; ++n)
        Bv[nxt][n] = *(const short8*)(bbase + (size_t)n * WTILE_E + (s + 1) * 512);
    }
    // ...then PIN them above this step's compute: scheduler may not sink
    // the loads past this point (defeats double-buffer collapse).
    __builtin_amdgcn_sched_barrier(0);

    short8 a0, a1;
#pragma unroll
    for (int i = 0; i < 4; ++i) {
      a0[i]     = (short)f2bf(Am0[cur][0][i]);
      a0[i + 4] = (short)f2bf(Am0[cur][1][i]);
      a1[i]     = (short)f2bf(Am1[cur][0][i]);
      a1[i + 4] = (short)f2bf(Am1[cur][1][i]);
    }
#pragma unroll
    for (int n = 0; n < 11; ++n) {
      acc0[n] = __builtin_amdgcn_mfma_f32_16x16x32_bf16(a0, Bv[cur][n], acc0[n], 0, 0, 0);
      acc1[n] = __builtin_amdgcn_mfma_f32_16x16x32_bf16(a1, Bv[cur][n], acc1[n], 0, 0, 0);
    }
  }

  // two-phase 8-way reduce; wave w finalizes n = w and n = w+8 (<11)
#pragma unroll
  for (int ph = 0; ph < 2; ++ph) {
#pragma unroll
    for (int n = 0; n < 11; ++n)
      red[wid][n][lane] = ph == 0 ? acc0[n] : acc1[n];
    __syncthreads();
    unsigned short* cb = Cb + (size_t)((row0 >> 4) + ph) * TILE_E + (lr & 7);
#pragma unroll
    for (int g = 0; g < 2; ++g) {
      int n = wid + g * 8;
      if (n < 11) {
        f32x4 t = red[0][n][lane];
#pragma unroll
        for (int w = 1; w < 8; ++w) {
          f32x4 p = red[w][n][lane];
#pragma unroll
          for (int r = 0; r < 4; ++r) t[r] += p[r];
        }
        int oct = n * 2 + (lr >> 3);
#pragma unroll
        for (int r = 0; r < 4; ++r)
          cb[oct * 128 + (lo * 4 + r) * 8] = f2bf(t[r]);
      }
    }
    __syncthreads();
  }
}

// ---------------- Kernel 3: score v7 — 16x512 block tile (R14 best) ---------
__global__ __launch_bounds__(256) void score_kernel(const unsigned short* __restrict__ Cb,
                                                    float* __restrict__ out) {
  int b = blockIdx.z;
  int wid  = threadIdx.x >> 6;
  int lane = threadIdx.x & 63;
  int lr = lane & 15, lo = lane >> 4;
  int t_base = blockIdx.y * 16;
  int s_base = blockIdx.x * 512 + wid * 128;

  const unsigned short* C2 = Cb + (size_t)b * (T_ / 16) * TILE_E;
  float* O = out + (size_t)b * T_ * T_;

  const unsigned short* Ct = C2 + (size_t)(t_base >> 4) * TILE_E;

  // q-fragments + w for this block's single m-tile
  short8 af[H_];
#pragma unroll
  for (int h = 0; h < H_; ++h)
    af[h] = *(const short8*)(Ct + (h * 4 + lo) * 128 + lr * 8);

  float wv[4][H_];
#pragma unroll
  for (int r = 0; r < 4; ++r) {
    short4v wr = *(const short4v*)(Ct + 20 * 128 + lo * 32 + r * 8);
#pragma unroll
    for (int h = 0; h < H_; ++h) wv[r][h] = bf2f((unsigned short)wr[h]);
  }

  // k-fragments for this wave's 8 s-tiles
  short8 bf[8];
#pragma unroll
  for (int n = 0; n < 8; ++n)
    bf[n] = *(const short8*)(C2 + (size_t)((s_base >> 4) + n) * TILE_E +
                             (16 + lo) * 128 + lr * 8);

  const f32x4 zero = (f32x4){0.f, 0.f, 0.f, 0.f};

  int tc = t_base + lo * 4;
  float* rowp[4];
#pragma unroll
  for (int r = 0; r < 4; ++r)
    rowp[r] = O + (size_t)(tc + r) * T_ + s_base + lr;

#pragma unroll
  for (int n = 0; n < 8; ++n) {
    f32x4 o = zero;
#pragma unroll
    for (int h = 0; h < H_; ++h) {
      f32x4 c = __builtin_amdgcn_mfma_f32_16x16x32_bf16(af[h], bf[n], zero, 0, 0, 0);
#pragma unroll
      for (int r = 0; r < 4; ++r) o[r] += wv[r][h] * fmaxf(c[r], 0.f);
    }
#pragma unroll
    for (int r = 0; r < 4; ++r)
      rowp[r][n * 16] = o[r];   // compile-time offset -> store immediate
  }
}

// ---------------------------------------------------------------------------
extern "C" void kernel_launch(void* const* d_in, const int* in_sizes, int n_in,
                              void* d_out, int out_size, void* d_ws, size_t ws_size,
                              hipStream_t stream) {
  const float* hs = (const float*)d_in[0];
  const float* Wq = (const float*)d_in[1];
  const float* Ww = (const float*)d_in[2];
  const float* Wk = (const float*)d_in[3];
  float* out = (float*)d_out;

  unsigned short* Wcb = (unsigned short*)d_ws;                      // 720,896 B
  unsigned short* Cb  = (unsigned short*)((char*)d_ws + (1 << 20)); // 2,883,584 B

  pack_weights<<<NC, 256, 0, stream>>>(Wq, Ww, Wk, Wcb);
  proj_kernel<<<ROWS / 32, 512, 0, stream>>>(hs, Wcb, Cb);
  dim3 g(T_ / 512, T_ / 16, B_);
  score_kernel<<<g, 256, 0, stream>>>(Cb, out);
}

// Round 19
// 54.217 us; speedup vs baseline: 1.2207x; 1.0746x over previous
//
#include <hip/hip_runtime.h>
#include <hip/hip_bf16.h>

#define B_ 2
#define T_ 4096
#define D_ 2048
#define H_ 4
#define NC 176            // combined proj cols: 128 q | 32 k | 4 w | 12 pad
#define ROWS (B_ * T_)    // 8192
#define TILE_E (16 * NC)  // 2816 elems per 16-row tile of Cb2
#define WTILE_E (16 * D_) // 32768 elems per 16-row n-tile of Wcb2

typedef __attribute__((ext_vector_type(8))) short short8;   // 8 x bf16
typedef __attribute__((ext_vector_type(4))) short short4v;  // 4 x bf16
typedef __attribute__((ext_vector_type(4))) float f32x4;
typedef __attribute__((ext_vector_type(4))) float float4v;

__device__ inline unsigned short f2bf(float f) {
  unsigned u = __float_as_uint(f);
  u += 0x7fffu + ((u >> 16) & 1u);   // RNE
  return (unsigned short)(u >> 16);
}
__device__ inline float bf2f(unsigned short s) {
  return __uint_as_float(((unsigned)s) << 16);
}

// ---------------- Kernel 1: pack weights into octet-tiled bf16 (vectorized) -
// Wcb2 layout: E(n, r, k) = n*32768 + (k>>3)*128 + r*8 + (k&7)
__global__ __launch_bounds__(256) void pack_weights(const float* __restrict__ Wq,
                                                    const float* __restrict__ Ww,
                                                    const float* __restrict__ Wk,
                                                    unsigned short* __restrict__ Wcb) {
  int row = blockIdx.x;          // 0..175
  int cg  = threadIdx.x;         // 0..255 (D_/8 octets)
  int col = cg * 8;

  const float* src = nullptr;
  if (row < 128)       src = Wq + (size_t)row * D_;
  else if (row < 160)  src = Wk + (size_t)(row - 128) * D_;
  else if (row < 164)  src = Ww + (size_t)(row - 160) * D_;

  short8 v;
  if (src) {
    float4v f0 = *(const float4v*)(src + col);
    float4v f1 = *(const float4v*)(src + col + 4);
#pragma unroll
    for (int i = 0; i < 4; ++i) {
      v[i]     = (short)f2bf(f0[i]);
      v[i + 4] = (short)f2bf(f1[i]);
    }
  } else {
#pragma unroll
    for (int i = 0; i < 8; ++i) v[i] = 0;
  }
  int n = row >> 4, r = row & 15;
  *(short8*)&Wcb[(size_t)n * WTILE_E + (size_t)cg * 128 + r * 8] = v;
}

// ---------------- Kernel 2: proj v8 (R14 best) + XCD swizzle ----------------
// M_rep=2 x split-K=8. 256 blocks x 8 waves (512 thr). Block = 32 rows;
// wave w owns K-chunk [w*256,(w+1)*256) for BOTH m-tiles (B reuse x2).
// XCD swizzle: XCD k owns 32 CONSECUTIVE 32-row groups -> its A stream is
// one contiguous ~2MB region. 256 % 8 == 0 -> bijective.
// NOTE: (512,2) — (512,4) caps VGPR at 128 -> spill (R13). Do not tighten.
__global__ __launch_bounds__(512, 2) void proj_kernel(const float* __restrict__ hs,
                                                      const unsigned short* __restrict__ Wcb,
                                                      unsigned short* __restrict__ Cb) {
  __shared__ f32x4 red[8][11][64];   // 90,112 B -> 1 block/CU (8 waves/CU)

  int wid  = threadIdx.x >> 6;
  int lane = threadIdx.x & 63;
  int lr = lane & 15, lo = lane >> 4;
  int bid  = blockIdx.x;
  int mb   = (bid & 7) * 32 + (bid >> 3);   // XCD-contiguous m-group
  int row0 = mb * 32;
  int k0   = wid * 256;

  const float* ap0 = hs + (size_t)(row0 + lr) * D_ + k0 + lo * 8;
  const float* ap1 = ap0 + (size_t)16 * D_;
  const unsigned short* bbase = Wcb + (size_t)k0 * 16 + lo * 128 + lr * 8;

  f32x4 acc0[11], acc1[11];
#pragma unroll
  for (int n = 0; n < 11; ++n) {
    acc0[n] = (f32x4){0.f, 0.f, 0.f, 0.f};
    acc1[n] = (f32x4){0.f, 0.f, 0.f, 0.f};
  }

  float4v Am0[2][2], Am1[2][2];   // [buf][half]
  short8  Bv[2][11];

  Am0[0][0] = *(const float4v*)(ap0);
  Am0[0][1] = *(const float4v*)(ap0 + 4);
  Am1[0][0] = *(const float4v*)(ap1);
  Am1[0][1] = *(const float4v*)(ap1 + 4);
#pragma unroll
  for (int n = 0; n < 11; ++n)
    Bv[0][n] = *(const short8*)(bbase + (size_t)n * WTILE_E);

#pragma unroll
  for (int s = 0; s < 8; ++s) {
    const int cur = s & 1, nxt = cur ^ 1;
    if (s < 7) {   // issue next-step loads BEFORE this step's MFMAs
      Am0[nxt][0] = *(const float4v*)(ap0 + (s + 1) * 32);
      Am0[nxt][1] = *(const float4v*)(ap0 + (s + 1) * 32 + 4);
      Am1[nxt][0] = *(const float4v*)(ap1 + (s + 1) * 32);
      Am1[nxt][1] = *(const float4v*)(ap1 + (s + 1) * 32 + 4);
#pragma unroll
      for (int n = 0; n < 11; ++n)
        Bv[nxt][n] = *(const short8*)(bbase + (size_t)n * WTILE_E + (s + 1) * 512);
    }
    short8 a0, a1;
#pragma unroll
    for (int i = 0; i < 4; ++i) {
      a0[i]     = (short)f2bf(Am0[cur][0][i]);
      a0[i + 4] = (short)f2bf(Am0[cur][1][i]);
      a1[i]     = (short)f2bf(Am1[cur][0][i]);
      a1[i + 4] = (short)f2bf(Am1[cur][1][i]);
    }
#pragma unroll
    for (int n = 0; n < 11; ++n) {
      acc0[n] = __builtin_amdgcn_mfma_f32_16x16x32_bf16(a0, Bv[cur][n], acc0[n], 0, 0, 0);
      acc1[n] = __builtin_amdgcn_mfma_f32_16x16x32_bf16(a1, Bv[cur][n], acc1[n], 0, 0, 0);
    }
  }

  // two-phase 8-way reduce; wave w finalizes n = w and n = w+8 (<11)
#pragma unroll
  for (int ph = 0; ph < 2; ++ph) {
#pragma unroll
    for (int n = 0; n < 11; ++n)
      red[wid][n][lane] = ph == 0 ? acc0[n] : acc1[n];
    __syncthreads();
    unsigned short* cb = Cb + (size_t)((row0 >> 4) + ph) * TILE_E + (lr & 7);
#pragma unroll
    for (int g = 0; g < 2; ++g) {
      int n = wid + g * 8;
      if (n < 11) {
        f32x4 t = red[0][n][lane];
#pragma unroll
        for (int w = 1; w < 8; ++w) {
          f32x4 p = red[w][n][lane];
#pragma unroll
          for (int r = 0; r < 4; ++r) t[r] += p[r];
        }
        int oct = n * 2 + (lr >> 3);
#pragma unroll
        for (int r = 0; r < 4; ++r)
          cb[oct * 128 + (lo * 4 + r) * 8] = f2bf(t[r]);
      }
    }
    __syncthreads();
  }
}

// ---------------- Kernel 3: score v7 (R14 best) + XCD swizzle ---------------
// Grid (2048,1,2); sid = (bid&7)*256 + (bid>>3) (bijective 8x256 transpose).
// XCD k owns t-tiles [k*32,(k+1)*32) x all s -> contiguous 512-row output
// band (~8MB write region per XCD), q-fragment L2 reuse x8.
// R18 BUG WAS HERE: grid.x was 512 (quarter of output unwritten) — now 2048.
__global__ __launch_bounds__(256) void score_kernel(const unsigned short* __restrict__ Cb,
                                                    float* __restrict__ out) {
  int b = blockIdx.z;
  int bid = blockIdx.x;
  int sid = (bid & 7) * 256 + (bid >> 3);
  int sx  = sid & 7;          // s-chunk index (0..7)
  int sy  = sid >> 3;         // t-tile index (0..255)

  int wid  = threadIdx.x >> 6;
  int lane = threadIdx.x & 63;
  int lr = lane & 15, lo = lane >> 4;
  int t_base = sy * 16;
  int s_base = sx * 512 + wid * 128;

  const unsigned short* C2 = Cb + (size_t)b * (T_ / 16) * TILE_E;
  float* O = out + (size_t)b * T_ * T_;

  const unsigned short* Ct = C2 + (size_t)(t_base >> 4) * TILE_E;

  // q-fragments + w for this block's single m-tile
  short8 af[H_];
#pragma unroll
  for (int h = 0; h < H_; ++h)
    af[h] = *(const short8*)(Ct + (h * 4 + lo) * 128 + lr * 8);

  float wv[4][H_];
#pragma unroll
  for (int r = 0; r < 4; ++r) {
    short4v wr = *(const short4v*)(Ct + 20 * 128 + lo * 32 + r * 8);
#pragma unroll
    for (int h = 0; h < H_; ++h) wv[r][h] = bf2f((unsigned short)wr[h]);
  }

  // k-fragments for this wave's 8 s-tiles
  short8 bf[8];
#pragma unroll
  for (int n = 0; n < 8; ++n)
    bf[n] = *(const short8*)(C2 + (size_t)((s_base >> 4) + n) * TILE_E +
                             (16 + lo) * 128 + lr * 8);

  const f32x4 zero = (f32x4){0.f, 0.f, 0.f, 0.f};

  int tc = t_base + lo * 4;
  float* rowp[4];
#pragma unroll
  for (int r = 0; r < 4; ++r)
    rowp[r] = O + (size_t)(tc + r) * T_ + s_base + lr;

#pragma unroll
  for (int n = 0; n < 8; ++n) {
    f32x4 o = zero;
#pragma unroll
    for (int h = 0; h < H_; ++h) {
      f32x4 c = __builtin_amdgcn_mfma_f32_16x16x32_bf16(af[h], bf[n], zero, 0, 0, 0);
#pragma unroll
      for (int r = 0; r < 4; ++r) o[r] += wv[r][h] * fmaxf(c[r], 0.f);
    }
#pragma unroll
    for (int r = 0; r < 4; ++r)
      rowp[r][n * 16] = o[r];   // compile-time offset -> store immediate
  }
}

// ---------------------------------------------------------------------------
extern "C" void kernel_launch(void* const* d_in, const int* in_sizes, int n_in,
                              void* d_out, int out_size, void* d_ws, size_t ws_size,
                              hipStream_t stream) {
  const float* hs = (const float*)d_in[0];
  const float* Wq = (const float*)d_in[1];
  const float* Ww = (const float*)d_in[2];
  const float* Wk = (const float*)d_in[3];
  float* out = (float*)d_out;

  unsigned short* Wcb = (unsigned short*)d_ws;                      // 720,896 B
  unsigned short* Cb  = (unsigned short*)((char*)d_ws + (1 << 20)); // 2,883,584 B

  pack_weights<<<NC, 256, 0, stream>>>(Wq, Ww, Wk, Wcb);
  proj_kernel<<<ROWS / 32, 512, 0, stream>>>(hs, Wcb, Cb);
  dim3 g((T_ / 16) * (T_ / 512), 1, B_);   // 256 * 8 = 2048 blocks in x
  score_kernel<<<g, 256, 0, stream>>>(Cb, out);
}

// Round 20
// 53.818 us; speedup vs baseline: 1.2297x; 1.0074x over previous
//
#include <hip/hip_runtime.h>
#include <hip/hip_bf16.h>

#define B_ 2
#define T_ 4096
#define D_ 2048
#define H_ 4
#define NC 176            // combined proj cols: 128 q | 32 k | 4 w | 12 pad
#define ROWS (B_ * T_)    // 8192
#define TILE_E (16 * NC)  // 2816 elems per 16-row tile of Cb2
#define WTILE_E (16 * D_) // 32768 elems per 16-row n-tile of Wcb2

typedef __attribute__((ext_vector_type(8))) short short8;   // 8 x bf16
typedef __attribute__((ext_vector_type(4))) short short4v;  // 4 x bf16
typedef __attribute__((ext_vector_type(4))) float f32x4;
typedef __attribute__((ext_vector_type(4))) float float4v;

__device__ inline unsigned short f2bf(float f) {
  unsigned u = __float_as_uint(f);
  u += 0x7fffu + ((u >> 16) & 1u);   // RNE
  return (unsigned short)(u >> 16);
}
__device__ inline float bf2f(unsigned short s) {
  return __uint_as_float(((unsigned)s) << 16);
}

// ---------------- Kernel 1: pack weights into octet-tiled bf16 (vectorized) -
// Wcb2 layout: E(n, r, k) = n*32768 + (k>>3)*128 + r*8 + (k&7)
__global__ __launch_bounds__(256) void pack_weights(const float* __restrict__ Wq,
                                                    const float* __restrict__ Ww,
                                                    const float* __restrict__ Wk,
                                                    unsigned short* __restrict__ Wcb) {
  int row = blockIdx.x;          // 0..175
  int cg  = threadIdx.x;         // 0..255 (D_/8 octets)
  int col = cg * 8;

  const float* src = nullptr;
  if (row < 128)       src = Wq + (size_t)row * D_;
  else if (row < 160)  src = Wk + (size_t)(row - 128) * D_;
  else if (row < 164)  src = Ww + (size_t)(row - 160) * D_;

  short8 v;
  if (src) {
    float4v f0 = *(const float4v*)(src + col);
    float4v f1 = *(const float4v*)(src + col + 4);
#pragma unroll
    for (int i = 0; i < 4; ++i) {
      v[i]     = (short)f2bf(f0[i]);
      v[i + 4] = (short)f2bf(f1[i]);
    }
  } else {
#pragma unroll
    for (int i = 0; i < 8; ++i) v[i] = 0;
  }
  int n = row >> 4, r = row & 15;
  *(short8*)&Wcb[(size_t)n * WTILE_E + (size_t)cg * 128 + r * 8] = v;
}

// ---------------- Kernel 2: proj v8 + XCD swizzle (R19 best; UNCHANGED) -----
// M_rep=2 x split-K=8. 256 blocks x 8 waves (512 thr). Block = 32 rows;
// wave w owns K-chunk [w*256,(w+1)*256) for BOTH m-tiles (B reuse x2).
// XCD swizzle: XCD k owns 32 CONSECUTIVE 32-row groups. 256 % 8 == 0.
// NOTE: (512,2) — (512,4) caps VGPR at 128 -> spill (R13). Do not tighten.
__global__ __launch_bounds__(512, 2) void proj_kernel(const float* __restrict__ hs,
                                                      const unsigned short* __restrict__ Wcb,
                                                      unsigned short* __restrict__ Cb) {
  __shared__ f32x4 red[8][11][64];   // 90,112 B -> 1 block/CU (8 waves/CU)

  int wid  = threadIdx.x >> 6;
  int lane = threadIdx.x & 63;
  int lr = lane & 15, lo = lane >> 4;
  int bid  = blockIdx.x;
  int mb   = (bid & 7) * 32 + (bid >> 3);   // XCD-contiguous m-group
  int row0 = mb * 32;
  int k0   = wid * 256;

  const float* ap0 = hs + (size_t)(row0 + lr) * D_ + k0 + lo * 8;
  const float* ap1 = ap0 + (size_t)16 * D_;
  const unsigned short* bbase = Wcb + (size_t)k0 * 16 + lo * 128 + lr * 8;

  f32x4 acc0[11], acc1[11];
#pragma unroll
  for (int n = 0; n < 11; ++n) {
    acc0[n] = (f32x4){0.f, 0.f, 0.f, 0.f};
    acc1[n] = (f32x4){0.f, 0.f, 0.f, 0.f};
  }

  float4v Am0[2][2], Am1[2][2];   // [buf][half]
  short8  Bv[2][11];

  Am0[0][0] = *(const float4v*)(ap0);
  Am0[0][1] = *(const float4v*)(ap0 + 4);
  Am1[0][0] = *(const float4v*)(ap1);
  Am1[0][1] = *(const float4v*)(ap1 + 4);
#pragma unroll
  for (int n = 0; n < 11; ++n)
    Bv[0][n] = *(const short8*)(bbase + (size_t)n * WTILE_E);

#pragma unroll
  for (int s = 0; s < 8; ++s) {
    const int cur = s & 1, nxt = cur ^ 1;
    if (s < 7) {   // issue next-step loads BEFORE this step's MFMAs
      Am0[nxt][0] = *(const float4v*)(ap0 + (s + 1) * 32);
      Am0[nxt][1] = *(const float4v*)(ap0 + (s + 1) * 32 + 4);
      Am1[nxt][0] = *(const float4v*)(ap1 + (s + 1) * 32);
      Am1[nxt][1] = *(const float4v*)(ap1 + (s + 1) * 32 + 4);
#pragma unroll
      for (int n = 0; n < 11; ++n)
        Bv[nxt][n] = *(const short8*)(bbase + (size_t)n * WTILE_E + (s + 1) * 512);
    }
    short8 a0, a1;
#pragma unroll
    for (int i = 0; i < 4; ++i) {
      a0[i]     = (short)f2bf(Am0[cur][0][i]);
      a0[i + 4] = (short)f2bf(Am0[cur][1][i]);
      a1[i]     = (short)f2bf(Am1[cur][0][i]);
      a1[i + 4] = (short)f2bf(Am1[cur][1][i]);
    }
#pragma unroll
    for (int n = 0; n < 11; ++n) {
      acc0[n] = __builtin_amdgcn_mfma_f32_16x16x32_bf16(a0, Bv[cur][n], acc0[n], 0, 0, 0);
      acc1[n] = __builtin_amdgcn_mfma_f32_16x16x32_bf16(a1, Bv[cur][n], acc1[n], 0, 0, 0);
    }
  }

  // two-phase 8-way reduce; wave w finalizes n = w and n = w+8 (<11)
#pragma unroll
  for (int ph = 0; ph < 2; ++ph) {
#pragma unroll
    for (int n = 0; n < 11; ++n)
      red[wid][n][lane] = ph == 0 ? acc0[n] : acc1[n];
    __syncthreads();
    unsigned short* cb = Cb + (size_t)((row0 >> 4) + ph) * TILE_E + (lr & 7);
#pragma unroll
    for (int g = 0; g < 2; ++g) {
      int n = wid + g * 8;
      if (n < 11) {
        f32x4 t = red[0][n][lane];
#pragma unroll
        for (int w = 1; w < 8; ++w) {
          f32x4 p = red[w][n][lane];
#pragma unroll
          for (int r = 0; r < 4; ++r) t[r] += p[r];
        }
        int oct = n * 2 + (lr >> 3);
#pragma unroll
        for (int r = 0; r < 4; ++r)
          cb[oct * 128 + (lo * 4 + r) * 8] = f2bf(t[r]);
      }
    }
    __syncthreads();
  }
}

// ---------------- Kernel 3: score v8 — 32x512 block (512 thr) + XCD swizzle -
// Block = 32 t-rows x 512 s-cols; 8 waves = 2 m-tiles (wm) x 4 s-chunks (wn).
// Per-wave body identical to v7 (same VGPR, same 2KB-row stores); block now
// owns a 32-row write band (2x the contiguous region of v7).
// Grid (1024,1,2); sid = (bid&7)*128 + (bid>>3) (bijective; XCD k owns a
// contiguous 512-row output band, as in R19).
__global__ __launch_bounds__(512) void score_kernel(const unsigned short* __restrict__ Cb,
                                                    float* __restrict__ out) {
  int b = blockIdx.z;
  int bid = blockIdx.x;
  int sid = (bid & 7) * 128 + (bid >> 3);
  int sx  = sid & 7;          // s-chunk-of-512 index (0..7)
  int sy  = sid >> 3;         // 32-row t-group index (0..127)

  int wid  = threadIdx.x >> 6;
  int wm   = wid >> 2;        // m-tile within block (0..1)
  int wn   = wid & 3;         // 128-col chunk within 512 (0..3)
  int lane = threadIdx.x & 63;
  int lr = lane & 15, lo = lane >> 4;
  int t_base = sy * 32 + wm * 16;
  int s_base = sx * 512 + wn * 128;

  const unsigned short* C2 = Cb + (size_t)b * (T_ / 16) * TILE_E;
  float* O = out + (size_t)b * T_ * T_;

  const unsigned short* Ct = C2 + (size_t)(t_base >> 4) * TILE_E;

  // q-fragments + w for this wave's m-tile
  short8 af[H_];
#pragma unroll
  for (int h = 0; h < H_; ++h)
    af[h] = *(const short8*)(Ct + (h * 4 + lo) * 128 + lr * 8);

  float wv[4][H_];
#pragma unroll
  for (int r = 0; r < 4; ++r) {
    short4v wr = *(const short4v*)(Ct + 20 * 128 + lo * 32 + r * 8);
#pragma unroll
    for (int h = 0; h < H_; ++h) wv[r][h] = bf2f((unsigned short)wr[h]);
  }

  // k-fragments for this wave's 8 s-tiles
  short8 bf[8];
#pragma unroll
  for (int n = 0; n < 8; ++n)
    bf[n] = *(const short8*)(C2 + (size_t)((s_base >> 4) + n) * TILE_E +
                             (16 + lo) * 128 + lr * 8);

  const f32x4 zero = (f32x4){0.f, 0.f, 0.f, 0.f};

  int tc = t_base + lo * 4;
  float* rowp[4];
#pragma unroll
  for (int r = 0; r < 4; ++r)
    rowp[r] = O + (size_t)(tc + r) * T_ + s_base + lr;

#pragma unroll
  for (int n = 0; n < 8; ++n) {
    f32x4 o = zero;
#pragma unroll
    for (int h = 0; h < H_; ++h) {
      f32x4 c = __builtin_amdgcn_mfma_f32_16x16x32_bf16(af[h], bf[n], zero, 0, 0, 0);
#pragma unroll
      for (int r = 0; r < 4; ++r) o[r] += wv[r][h] * fmaxf(c[r], 0.f);
    }
#pragma unroll
    for (int r = 0; r < 4; ++r)
      rowp[r][n * 16] = o[r];   // compile-time offset -> store immediate
  }
}

// ---------------------------------------------------------------------------
extern "C" void kernel_launch(void* const* d_in, const int* in_sizes, int n_in,
                              void* d_out, int out_size, void* d_ws, size_t ws_size,
                              hipStream_t stream) {
  const float* hs = (const float*)d_in[0];
  const float* Wq = (const float*)d_in[1];
  const float* Ww = (const float*)d_in[2];
  const float* Wk = (const float*)d_in[3];
  float* out = (float*)d_out;

  unsigned short* Wcb = (unsigned short*)d_ws;                      // 720,896 B
  unsigned short* Cb  = (unsigned short*)((char*)d_ws + (1 << 20)); // 2,883,584 B

  pack_weights<<<NC, 256, 0, stream>>>(Wq, Ww, Wk, Wcb);
  proj_kernel<<<ROWS / 32, 512, 0, stream>>>(hs, Wcb, Cb);
  dim3 g((T_ / 32) * (T_ / 512), 1, B_);   // 128 * 8 = 1024 blocks in x
  score_kernel<<<g, 512, 0, stream>>>(Cb, out);
}